// Round 6
// baseline (556.122 us; speedup 1.0000x reference)
//
#include <hip/hip_runtime.h>

// r12: resubmit of r11 (node-per-wave GAT) — r11 died at GPU acquisition
// (infra, "at capacity"), no on-GPU verdict. Source unchanged; re-audited:
// lane=(th,b) mapping, shfl_xor(32) pairing, pad-zeroing, prefetch tail all ok.
// lane=(th,b): 32 batches x 2 feat-halves; one edge = 3 float2 wave-loads
// (1536B contiguous); csr prefetched 2-ahead, rows 1-ahead issued BEFORE
// compute -> latency overlapped. 4 cfgs per dispatch.

#define NN 10000
#define BB 32
#define EE 40000
#define HH 4
#define DD 10
#define TT 10
#define FS 12          // padded feats per (n,b) row (2 halves x 6)
#define NEG 0.2f

#define NB   (NN*BB)          // 320000
#define NBT  (NN*BB*TT)       // 3200000
#define NBF  (NN*BB*FS)       // 3840000 padded feat elems per buffer

// ---------------- extract mu/sigma (transposed layout) + regression -------
// layout: buf[((n*2+th)*32 + b)*6 + j], t = th*6+j, pads (t>=10) zeroed.
__global__ void extract_kernel(const float* __restrict__ x,
                               const float* __restrict__ wmu, const float* __restrict__ bmu,
                               const float* __restrict__ wsg, const float* __restrict__ bsg,
                               float* __restrict__ muT, float* __restrict__ sgT,
                               float* __restrict__ regmu, float* __restrict__ regsg) {
    int i = blockIdx.x * blockDim.x + threadIdx.x;   // over N*B
    if (i >= NB) return;
    int n = i / BB, b = i % BB;
    float smu = 0.f, ssg = 0.f;
    float muv[FS], sgv[FS];
#pragma unroll
    for (int t = 0; t < TT; t++) {
        size_t xi = (((size_t)t * NN + n) * BB + b) * 3;
        float m = x[xi], s = x[xi + 1];
        muv[t] = m; sgv[t] = s;
        smu += m * wmu[t];
        ssg += s * wsg[t];
    }
    muv[10] = 0.f; muv[11] = 0.f; sgv[10] = 0.f; sgv[11] = 0.f;
#pragma unroll
    for (int t = 0; t < FS; t++) {
        int th = t / 6, j = t - th * 6;
        size_t di = ((size_t)(n * 2 + th) * BB + b) * 6 + j;
        muT[di] = muv[t];
        sgT[di] = sgv[t];
    }
    regmu[i] = smu + bmu[0];
    regsg[i] = ssg + bsg[0];
}

// ---------------- CSR build (both graphs in one dispatch) ----------------
__global__ void deg2_kernel(const int* __restrict__ dst0, int* __restrict__ deg0,
                            const int* __restrict__ dst1, int* __restrict__ deg1) {
    int e = blockIdx.x * blockDim.x + threadIdx.x;
    const int* dst = blockIdx.y ? dst1 : dst0;
    int* deg       = blockIdx.y ? deg1 : deg0;
    if (e < EE) atomicAdd(&deg[dst[e]], 1);
}

__global__ void scan2_kernel(const int* __restrict__ deg0, int* __restrict__ off0,
                             const int* __restrict__ deg1, int* __restrict__ off1) {
    const int* __restrict__ deg = blockIdx.x ? deg1 : deg0;
    int* __restrict__ off       = blockIdx.x ? off1 : off0;
    __shared__ int sm[16];
    __shared__ int carry_s;
    int tid = threadIdx.x;               // 1024 threads = 16 waves
    int lane = tid & 63, wid = tid >> 6;
    if (tid == 0) { carry_s = 0; off[0] = 0; }
    __syncthreads();
    for (int base = 0; base < NN; base += 1024) {
        int i = base + tid;
        int v = (i < NN) ? deg[i] : 0;
        int x = v;
#pragma unroll
        for (int s = 1; s < 64; s <<= 1) {
            int t = __shfl_up(x, s, 64);
            if (lane >= s) x += t;
        }
        if (lane == 63) sm[wid] = x;
        __syncthreads();
        if (wid == 0) {
            int w = (lane < 16) ? sm[lane] : 0;
#pragma unroll
            for (int s = 1; s < 16; s <<= 1) {
                int t = __shfl_up(w, s, 64);
                if (lane >= s) w += t;
            }
            if (lane < 16) sm[lane] = w;
        }
        __syncthreads();
        int add = carry_s + ((wid > 0) ? sm[wid - 1] : 0);
        if (i < NN) off[i + 1] = add + x;
        int total = sm[15];
        __syncthreads();
        if (tid == 0) carry_s += total;
        __syncthreads();
    }
}

__global__ void fill2_kernel(const int* __restrict__ src0, const int* __restrict__ dst0,
                             const int* __restrict__ off0, int* __restrict__ cur0,
                             int* __restrict__ csr0,
                             const int* __restrict__ src1, const int* __restrict__ dst1,
                             const int* __restrict__ off1, int* __restrict__ cur1,
                             int* __restrict__ csr1) {
    int e = blockIdx.x * blockDim.x + threadIdx.x;
    const int* src = blockIdx.y ? src1 : src0;
    const int* dst = blockIdx.y ? dst1 : dst0;
    const int* off = blockIdx.y ? off1 : off0;
    int* cursor    = blockIdx.y ? cur1 : cur0;
    int* csr       = blockIdx.y ? csr1 : csr0;
    if (e < EE) {
        int d = dst[e];
        int p = atomicAdd(&cursor[d], 1);
        csr[off[d] + p] = src[e];
    }
}

// ---------------- degree sort: counting sort into perm (descending deg) ---
__global__ void hist2_kernel(const int* __restrict__ deg0, const int* __restrict__ deg1,
                             int* __restrict__ hist) {
    __shared__ int lh[64];
    if (threadIdx.x < 64) lh[threadIdx.x] = 0;
    __syncthreads();
    int n = blockIdx.x * blockDim.x + threadIdx.x;
    int g = blockIdx.y;
    const int* deg = g ? deg1 : deg0;
    if (n < NN) {
        int d = deg[n];
        int bin = 63 - ((d < 63) ? d : 63);
        atomicAdd(&lh[bin], 1);
    }
    __syncthreads();
    if (threadIdx.x < 64 && lh[threadIdx.x])
        atomicAdd(&hist[g * 64 + threadIdx.x], lh[threadIdx.x]);
}

__global__ void binoff_kernel(const int* __restrict__ hist, int* __restrict__ boff) {
    int g = threadIdx.x >> 6, lane = threadIdx.x & 63;
    int v = hist[g * 64 + lane];
    int x = v;
#pragma unroll
    for (int s = 1; s < 64; s <<= 1) {
        int t = __shfl_up(x, s, 64);
        if (lane >= s) x += t;
    }
    boff[g * 64 + lane] = x - v;
}

__global__ void permfill2_kernel(const int* __restrict__ deg0, const int* __restrict__ deg1,
                                 const int* __restrict__ boff, int* __restrict__ bcur,
                                 int* __restrict__ perm0, int* __restrict__ perm1) {
    __shared__ int lh[64], lbase[64];
    if (threadIdx.x < 64) lh[threadIdx.x] = 0;
    __syncthreads();
    int n = blockIdx.x * blockDim.x + threadIdx.x;
    int g = blockIdx.y;
    const int* deg = g ? deg1 : deg0;
    int* perm      = g ? perm1 : perm0;
    int bin = 0, myp = 0;
    if (n < NN) {
        int d = deg[n];
        bin = 63 - ((d < 63) ? d : 63);
        myp = atomicAdd(&lh[bin], 1);
    }
    __syncthreads();
    if (threadIdx.x < 64) {
        int c = lh[threadIdx.x];
        lbase[threadIdx.x] = c ? atomicAdd(&bcur[g * 64 + threadIdx.x], c) : 0;
    }
    __syncthreads();
    if (n < NN) perm[boff[g * 64 + bin] + lbase[bin] + myp] = n;
}

// ---------------- precompute vl/vr for all 8 GATs ----------------
__global__ void vpre_kernel(const float* __restrict__ fc0, const float* __restrict__ al0, const float* __restrict__ ar0,
                            const float* __restrict__ fc1, const float* __restrict__ al1, const float* __restrict__ ar1,
                            const float* __restrict__ fc2, const float* __restrict__ al2, const float* __restrict__ ar2,
                            const float* __restrict__ fc3, const float* __restrict__ al3, const float* __restrict__ ar3,
                            float* __restrict__ vbuf) {
    int j = threadIdx.x;                 // 0..319
    if (j >= 320) return;
    int g = j / 40, r = j % 40;
    int h = r / 10, t = r % 10;
    int which = g & 3, layer = g >> 2;
    const float* fc; const float* al; const float* ar;
    if (which == 0)      { fc = fc0; al = al0; ar = ar0; }
    else if (which == 1) { fc = fc1; al = al1; ar = ar1; }
    else if (which == 2) { fc = fc2; al = al2; ar = ar2; }
    else                 { fc = fc3; al = al3; ar = ar3; }
    fc += layer * (HH * DD * TT);
    al += layer * (HH * DD);
    ar += layer * (HH * DD);
    float vl = 0.f, vr = 0.f;
#pragma unroll
    for (int d = 0; d < DD; d++) {
        float w = fc[(h * DD + d) * TT + t];
        vl += al[h * DD + d] * w;
        vr += ar[h * DD + d] * w;
    }
    vbuf[g * 80 + r] = vl;
    vbuf[g * 80 + 40 + r] = vr;
}

// ---------------- node-per-wave quad-GAT ----------------------------------
struct QCfg {
    const float* f;        // transposed feats [(n*2+th)*32+b]*6
    const float* W;        // [H*D][T]
    const float* v;        // vl[40] | vr[40]
    const int* off; const int* csr; const int* perm;
    float* g; float* stats;
};
struct QCfg4 { QCfg c[4]; };

template <bool STATS>
__global__ void __launch_bounds__(256)
gatq_kernel(QCfg4 cfgs) {
    const QCfg cfg = cfgs.c[blockIdx.y];
    __shared__ __align__(16) float sW[HH * DD * 12];   // rows padded to 12, pads=0
    __shared__ float svp[2 * HH * 12];                 // vl/vr padded to 12, pads=0
    for (int kk = threadIdx.x; kk < HH * DD * 12; kk += blockDim.x) {
        int r = kk / 12, t = kk - r * 12;
        sW[kk] = (t < TT) ? cfg.W[r * TT + t] : 0.f;
    }
    if (threadIdx.x < 2 * HH * 12) {
        int s = threadIdx.x / 48, r = threadIdx.x % 48;
        int h = r / 12, t = r % 12;
        svp[threadIdx.x] = (t < TT) ? cfg.v[s * 40 + h * TT + t] : 0.f;
    }
    __syncthreads();

    int wid = threadIdx.x >> 6, lane = threadIdx.x & 63;
    int th = lane >> 5, b = lane & 31;
    int slot = blockIdx.x * 4 + wid;          // one node per wave
    float lsum = 0.f, lsq = 0.f;
    if (slot < NN) {
        int n = cfg.perm[slot];
        int s0 = cfg.off[n], s1 = cfg.off[n + 1];
        const float* __restrict__ f = cfg.f;
        const int*   __restrict__ csr = cfg.csr;

        // per-lane attention slices (pads are zero)
        float vl[HH][6];
#pragma unroll
        for (int h = 0; h < HH; h++)
#pragma unroll
            for (int j = 0; j < 6; j++) vl[h][j] = svp[h * 12 + th * 6 + j];

        // self row -> er
        float er[HH];
        {
            const float* p = f + ((size_t)n * 64 + lane) * 6;
            float2 a = *(const float2*)p;
            float2 c = *(const float2*)(p + 2);
            float2 d = *(const float2*)(p + 4);
            float fs[6] = {a.x, a.y, c.x, c.y, d.x, d.y};
#pragma unroll
            for (int h = 0; h < HH; h++) {
                float e = 0.f;
#pragma unroll
                for (int j = 0; j < 6; j++) e += svp[48 + h * 12 + th * 6 + j] * fs[j];
                e += __shfl_xor(e, 32, 64);
                er[h] = e;
            }
        }

        float acc[HH][6];
        float den[HH];
#pragma unroll
        for (int h = 0; h < HH; h++) {
            den[h] = 0.f;
#pragma unroll
            for (int j = 0; j < 6; j++) acc[h][j] = 0.f;
        }

        // edge loop: csr 2-ahead, rows 1-ahead issued BEFORE compute
        int e2 = 0;
        float2 n0, n1, n2;
        if (s0 < s1) {
            int e1 = csr[s0];
            const float* q = f + ((size_t)e1 * 64 + lane) * 6;
            n0 = *(const float2*)q; n1 = *(const float2*)(q + 2); n2 = *(const float2*)(q + 4);
            e2 = (s0 + 1 < s1) ? csr[s0 + 1] : e1;
        }
        for (int k = s0; k < s1; k++) {
            float cur[6] = {n0.x, n0.y, n1.x, n1.y, n2.x, n2.y};
            if (k + 1 < s1) {
                const float* q = f + ((size_t)e2 * 64 + lane) * 6;
                n0 = *(const float2*)q; n1 = *(const float2*)(q + 2); n2 = *(const float2*)(q + 4);
            }
            if (k + 2 < s1) e2 = csr[k + 2];
            float w[HH];
#pragma unroll
            for (int h = 0; h < HH; h++) {
                float el = 0.f;
#pragma unroll
                for (int j = 0; j < 6; j++) el += vl[h][j] * cur[j];
                el += __shfl_xor(el, 32, 64);
                float z = el + er[h];
                z = (z >= 0.f) ? z : NEG * z;
                float ww = __expf(z);
                w[h] = ww;
                den[h] += ww;
            }
#pragma unroll
            for (int h = 0; h < HH; h++)
#pragma unroll
                for (int j = 0; j < 6; j++) acc[h][j] += w[h] * cur[j];
        }

        bool nz = (s1 > s0);
        float outv[DD];
#pragma unroll
        for (int d = 0; d < DD; d++) outv[d] = 0.f;
#pragma unroll
        for (int h = 0; h < HH; h++) {
            float rd = nz ? (1.0f / den[h]) : 0.f;
            float yh[DD];
#pragma unroll
            for (int d = 0; d < DD; d++) {
                const float2* wp = (const float2*)&sW[(h * DD + d) * 12 + th * 6];
                float2 w0 = wp[0], w1 = wp[1], w2 = wp[2];
                yh[d] = w0.x * acc[h][0] + w0.y * acc[h][1]
                      + w1.x * acc[h][2] + w1.y * acc[h][3]
                      + w2.x * acc[h][4] + w2.y * acc[h][5];
            }
#pragma unroll
            for (int d = 0; d < DD; d++) {
                float y = yh[d] + __shfl_xor(yh[d], 32, 64);
                y *= rd;
                y = (y >= 0.f) ? y : NEG * y;
                outv[d] += 0.25f * y;
            }
        }

        if (th == 0) {
            float* gp = cfg.g + ((size_t)n * BB + b) * DD;
#pragma unroll
            for (int d = 0; d < DD; d += 2)
                *(float2*)(gp + d) = make_float2(outv[d], outv[d + 1]);
            if (STATS) {
#pragma unroll
                for (int d = 0; d < DD; d++) { lsum += outv[d]; lsq += outv[d] * outv[d]; }
            }
        }
    }
    if (STATS) {
#pragma unroll
        for (int o = 32; o > 0; o >>= 1) {
            lsum += __shfl_down(lsum, o, 64);
            lsq  += __shfl_down(lsq, o, 64);
        }
        __shared__ float ss[4][2];
        int lid = threadIdx.x & 63;
        if (lid == 0) { ss[threadIdx.x >> 6][0] = lsum; ss[threadIdx.x >> 6][1] = lsq; }
        __syncthreads();
        if (threadIdx.x == 0) {
            float a0 = 0.f, a1 = 0.f;
#pragma unroll
            for (int w = 0; w < 4; w++) { a0 += ss[w][0]; a1 += ss[w][1]; }
            atomicAdd(&cfg.stats[0], a0);
            atomicAdd(&cfg.stats[1], a1);
        }
    }
}

// ---------------- LN(A), LN(B), average; writes transposed feat layout ----
__global__ void lncomb2_kernel(const float* __restrict__ gA, const float* __restrict__ gB,
                               const float* __restrict__ gA2, const float* __restrict__ gB2,
                               const float* __restrict__ stats,
                               float* __restrict__ hp, float* __restrict__ hrl) {
    int i = blockIdx.x * blockDim.x + threadIdx.x;   // over NB*12
    if (i >= NB * FS) return;
    const float* ga = blockIdx.y ? gA2 : gA;
    const float* gb = blockIdx.y ? gB2 : gB;
    const float* st = stats + (blockIdx.y ? 4 : 0);
    float* h        = blockIdx.y ? hrl : hp;
    int nb = i / FS, t = i - nb * FS;
    float val = 0.f;
    if (t < TT) {
        const float M = (float)NBT;
        float ma = st[0] / M; float va = st[1] / M - ma * ma;
        float mb = st[2] / M; float vb = st[3] / M - mb * mb;
        float ra = rsqrtf(va + 1e-5f), rb = rsqrtf(vb + 1e-5f);
        float a = ga[(size_t)nb * DD + t], bb = gb[(size_t)nb * DD + t];
        val = 0.5f * ((a - ma) * ra + (bb - mb) * rb);
    }
    int n = nb >> 5, b = nb & 31;
    int tth = t / 6, j = t - tth * 6;
    h[((size_t)(n * 2 + tth) * BB + b) * 6 + j] = val;
}

// ---------------- final combine, both outputs in one dispatch -------------
__global__ void outcomb2_kernel(const float* __restrict__ regmu, const float* __restrict__ regsg,
                                const float* __restrict__ gA, const float* __restrict__ gA2,
                                const float* __restrict__ gB, const float* __restrict__ gB2,
                                float* __restrict__ out) {
    int i = blockIdx.x * blockDim.x + threadIdx.x;
    if (i >= NBT) return;
    int nb = i / DD;
    if (blockIdx.y == 0) out[i]       = (regmu[nb] + gA[i] + gA2[i]) * (1.0f / 3.0f);
    else                 out[NBT + i] = (regsg[nb] + gB[i] + gB2[i]) * (1.0f / 3.0f);
}

extern "C" void kernel_launch(void* const* d_in, const int* in_sizes, int n_in,
                              void* d_out, int out_size, void* d_ws, size_t ws_size,
                              hipStream_t stream) {
    const float* x      = (const float*)d_in[0];
    const int* ps_src   = (const int*)d_in[1];
    const int* ps_dst   = (const int*)d_in[2];
    const int* rl_src   = (const int*)d_in[3];
    const int* rl_dst   = (const int*)d_in[4];
    const float* mu_p_fc = (const float*)d_in[5];
    const float* mu_p_al = (const float*)d_in[6];
    const float* mu_p_ar = (const float*)d_in[7];
    const float* sg_p_fc = (const float*)d_in[8];
    const float* sg_p_al = (const float*)d_in[9];
    const float* sg_p_ar = (const float*)d_in[10];
    const float* mu_r_fc = (const float*)d_in[11];
    const float* mu_r_al = (const float*)d_in[12];
    const float* mu_r_ar = (const float*)d_in[13];
    const float* sg_r_fc = (const float*)d_in[14];
    const float* sg_r_al = (const float*)d_in[15];
    const float* sg_r_ar = (const float*)d_in[16];
    const float* reg_mu_w = (const float*)d_in[17];
    const float* reg_mu_b = (const float*)d_in[18];
    const float* reg_sg_w = (const float*)d_in[19];
    const float* reg_sg_b = (const float*)d_in[20];

    float* out = (float*)d_out;

    // ---- workspace carve ----
    float* fw = (float*)d_ws;
    float* muT   = fw;              fw += NBF;   // transposed feats
    float* sgT   = fw;              fw += NBF;
    float* hpT   = fw;              fw += NBF;
    float* hrlT  = fw;              fw += NBF;
    float* gA    = fw;              fw += NBT;   // stride-10 GAT outputs
    float* gB    = fw;              fw += NBT;
    float* gA2   = fw;              fw += NBT;
    float* gB2   = fw;              fw += NBT;
    float* regmu = fw;              fw += NB;
    float* regsg = fw;              fw += NB;
    float* vbuf  = fw;              fw += 8 * 80;
    int* iw = (int*)fw;
    int* ps_off = iw;               iw += NN + 1;
    int* rl_off = iw;               iw += NN + 1;
    int* ps_csr = iw;               iw += EE;
    int* rl_csr = iw;               iw += EE;
    int* perm_ps = iw;              iw += NN;
    int* perm_rl = iw;              iw += NN;
    int* boff   = iw;               iw += 128;
    // zero region starts here:
    int* deg_ps = iw;               iw += NN;
    int* cur_ps = iw;               iw += NN;
    int* deg_rl = iw;               iw += NN;
    int* cur_rl = iw;               iw += NN;
    int* hist   = iw;               iw += 128;
    int* bcur   = iw;               iw += 128;
    float* stats = (float*)iw;      // 8 floats
    size_t zero_bytes = (size_t)(4 * NN + 256) * sizeof(int) + 8 * sizeof(float);
    hipMemsetAsync(deg_ps, 0, zero_bytes, stream);

    const int TPB = 256;
    const int GRID_NB  = (NB + TPB - 1) / TPB;          // 1250
    const int GRID_NBT = (NBT + TPB - 1) / TPB;
    const int GRID_NBF = (NB * FS + TPB - 1) / TPB;     // 15000
    const int GRID_E   = (EE + TPB - 1) / TPB;
    const int GRID_N   = (NN + TPB - 1) / TPB;          // 40
    const int GRID_Q   = (NN + 3) / 4;                  // 2500: 4 nodes/block

    extract_kernel<<<GRID_NB, TPB, 0, stream>>>(x, reg_mu_w, reg_mu_b, reg_sg_w, reg_sg_b,
                                                muT, sgT, regmu, regsg);

    // CSR + degree-sort for both graphs
    {
        dim3 g(GRID_E, 2, 1);
        dim3 gn(GRID_N, 2, 1);
        deg2_kernel<<<g, TPB, 0, stream>>>(ps_dst, deg_ps, rl_dst, deg_rl);
        scan2_kernel<<<2, 1024, 0, stream>>>(deg_ps, ps_off, deg_rl, rl_off);
        fill2_kernel<<<g, TPB, 0, stream>>>(ps_src, ps_dst, ps_off, cur_ps, ps_csr,
                                            rl_src, rl_dst, rl_off, cur_rl, rl_csr);
        hist2_kernel<<<gn, TPB, 0, stream>>>(deg_ps, deg_rl, hist);
        binoff_kernel<<<1, 128, 0, stream>>>(hist, boff);
        permfill2_kernel<<<gn, TPB, 0, stream>>>(deg_ps, deg_rl, boff, bcur, perm_ps, perm_rl);
    }

    vpre_kernel<<<1, 320, 0, stream>>>(mu_p_fc, mu_p_al, mu_p_ar,
                                       sg_p_fc, sg_p_al, sg_p_ar,
                                       mu_r_fc, mu_r_al, mu_r_ar,
                                       sg_r_fc, sg_r_al, sg_r_ar, vbuf);

    // ---- layer 0: 4 GATs, one dispatch ----
    {
        QCfg4 c;
        c.c[0] = { muT, mu_p_fc,       vbuf + 0 * 80, ps_off, ps_csr, perm_ps, gA,  stats + 0 };
        c.c[1] = { sgT, sg_p_fc,       vbuf + 1 * 80, ps_off, ps_csr, perm_ps, gB,  stats + 2 };
        c.c[2] = { muT, mu_r_fc,       vbuf + 2 * 80, rl_off, rl_csr, perm_rl, gA2, stats + 4 };
        c.c[3] = { sgT, sg_r_fc,       vbuf + 3 * 80, rl_off, rl_csr, perm_rl, gB2, stats + 6 };
        dim3 grid(GRID_Q, 4, 1);
        gatq_kernel<true><<<grid, TPB, 0, stream>>>(c);
    }
    {
        dim3 g(GRID_NBF, 2, 1);
        lncomb2_kernel<<<g, TPB, 0, stream>>>(gA, gB, gA2, gB2, stats, hpT, hrlT);
    }

    // ---- final layers: 4 GATs, one dispatch ----
    {
        QCfg4 c;
        c.c[0] = { hpT,  mu_p_fc + 400, vbuf + 4 * 80, ps_off, ps_csr, perm_ps, gA,  nullptr };
        c.c[1] = { hpT,  sg_p_fc + 400, vbuf + 5 * 80, ps_off, ps_csr, perm_ps, gB,  nullptr };
        c.c[2] = { hrlT, mu_r_fc + 400, vbuf + 6 * 80, rl_off, rl_csr, perm_rl, gA2, nullptr };
        c.c[3] = { hrlT, sg_r_fc + 400, vbuf + 7 * 80, rl_off, rl_csr, perm_rl, gB2, nullptr };
        dim3 grid(GRID_Q, 4, 1);
        gatq_kernel<false><<<grid, TPB, 0, stream>>>(c);
    }

    {
        dim3 g(GRID_NBT, 2, 1);
        outcomb2_kernel<<<g, TPB, 0, stream>>>(regmu, regsg, gA, gA2, gB, gB2, out);
    }
}

// Round 7
// 422.980 us; speedup vs baseline: 1.3148x; 1.3148x over previous
//
#include <hip/hip_runtime.h>
#include <hip/hip_fp16.h>

// r13: fp16 feature rows (halve scattered lane-addrs) + batch-group blocking
// (BSUB=2: co-resident blocks share a ~1MB L2-resident feature slice) +
// unroll-4 edge loop, on the proven r2/r4 pair-GAT structure.

#define NN 10000
#define BB 32
#define EE 40000
#define HH 4
#define DD 10
#define TT 10
#define NEG 0.2f

#define NB   (NN*BB)          // 320000
#define NBT  (NN*BB*TT)       // 3200000
#define BSUB 2
#define NGRP (NN*BSUB)        // 20000 -> 16 batch-groups

// fp16 rows: DUAL (mu|sg) = 24 halves (48B, 3x16B pieces); single = 16 halves (32B, 2x16B)

__device__ __forceinline__ float2 cvt2(unsigned u) {
    return __half22float2(*reinterpret_cast<const __half2*>(&u));
}
__device__ __forceinline__ void unpA(const uint4& u0, const uint4& u1, float (&fa)[10]) {
    float2 t;
    t = cvt2(u0.x); fa[0] = t.x; fa[1] = t.y;
    t = cvt2(u0.y); fa[2] = t.x; fa[3] = t.y;
    t = cvt2(u0.z); fa[4] = t.x; fa[5] = t.y;
    t = cvt2(u0.w); fa[6] = t.x; fa[7] = t.y;
    t = cvt2(u1.x); fa[8] = t.x; fa[9] = t.y;
}
__device__ __forceinline__ void unpB(const uint4& u1, const uint4& u2, float (&fb)[10]) {
    float2 t;
    t = cvt2(u1.z); fb[0] = t.x; fb[1] = t.y;
    t = cvt2(u1.w); fb[2] = t.x; fb[3] = t.y;
    t = cvt2(u2.x); fb[4] = t.x; fb[5] = t.y;
    t = cvt2(u2.y); fb[6] = t.x; fb[7] = t.y;
    t = cvt2(u2.z); fb[8] = t.x; fb[9] = t.y;
}

// ---------------- extract mu/sigma (fp16 interleaved) + regression --------
__global__ void extract_kernel(const float* __restrict__ x,
                               const float* __restrict__ wmu, const float* __restrict__ bmu,
                               const float* __restrict__ wsg, const float* __restrict__ bsg,
                               __half* __restrict__ msH,
                               float* __restrict__ regmu, float* __restrict__ regsg) {
    int i = blockIdx.x * blockDim.x + threadIdx.x;   // over N*B
    if (i >= NB) return;
    int n = i / BB, b = i % BB;
    float smu = 0.f, ssg = 0.f;
    float muv[TT], sgv[TT];
#pragma unroll
    for (int t = 0; t < TT; t++) {
        size_t xi = (((size_t)t * NN + n) * BB + b) * 3;
        float m = x[xi], s = x[xi + 1];
        muv[t] = m; sgv[t] = s;
        smu += m * wmu[t];
        ssg += s * wsg[t];
    }
    __half2* dst = (__half2*)(msH + (size_t)i * 24);
    dst[0] = __floats2half2_rn(muv[0], muv[1]);
    dst[1] = __floats2half2_rn(muv[2], muv[3]);
    dst[2] = __floats2half2_rn(muv[4], muv[5]);
    dst[3] = __floats2half2_rn(muv[6], muv[7]);
    dst[4] = __floats2half2_rn(muv[8], muv[9]);
    dst[5] = __floats2half2_rn(0.f, 0.f);
    dst[6] = __floats2half2_rn(sgv[0], sgv[1]);
    dst[7] = __floats2half2_rn(sgv[2], sgv[3]);
    dst[8] = __floats2half2_rn(sgv[4], sgv[5]);
    dst[9] = __floats2half2_rn(sgv[6], sgv[7]);
    dst[10] = __floats2half2_rn(sgv[8], sgv[9]);
    dst[11] = __floats2half2_rn(0.f, 0.f);
    regmu[i] = smu + bmu[0];
    regsg[i] = ssg + bsg[0];
}

// ---------------- CSR build (both graphs in one dispatch) ----------------
__global__ void deg2_kernel(const int* __restrict__ dst0, int* __restrict__ deg0,
                            const int* __restrict__ dst1, int* __restrict__ deg1) {
    int e = blockIdx.x * blockDim.x + threadIdx.x;
    const int* dst = blockIdx.y ? dst1 : dst0;
    int* deg       = blockIdx.y ? deg1 : deg0;
    if (e < EE) atomicAdd(&deg[dst[e]], 1);
}

__global__ void scan2_kernel(const int* __restrict__ deg0, int* __restrict__ off0,
                             const int* __restrict__ deg1, int* __restrict__ off1) {
    const int* __restrict__ deg = blockIdx.x ? deg1 : deg0;
    int* __restrict__ off       = blockIdx.x ? off1 : off0;
    __shared__ int sm[16];
    __shared__ int carry_s;
    int tid = threadIdx.x;               // 1024 threads = 16 waves
    int lane = tid & 63, wid = tid >> 6;
    if (tid == 0) { carry_s = 0; off[0] = 0; }
    __syncthreads();
    for (int base = 0; base < NN; base += 1024) {
        int i = base + tid;
        int v = (i < NN) ? deg[i] : 0;
        int x = v;
#pragma unroll
        for (int s = 1; s < 64; s <<= 1) {
            int t = __shfl_up(x, s, 64);
            if (lane >= s) x += t;
        }
        if (lane == 63) sm[wid] = x;
        __syncthreads();
        if (wid == 0) {
            int w = (lane < 16) ? sm[lane] : 0;
#pragma unroll
            for (int s = 1; s < 16; s <<= 1) {
                int t = __shfl_up(w, s, 64);
                if (lane >= s) w += t;
            }
            if (lane < 16) sm[lane] = w;
        }
        __syncthreads();
        int add = carry_s + ((wid > 0) ? sm[wid - 1] : 0);
        if (i < NN) off[i + 1] = add + x;
        int total = sm[15];
        __syncthreads();
        if (tid == 0) carry_s += total;
        __syncthreads();
    }
}

__global__ void fill2_kernel(const int* __restrict__ src0, const int* __restrict__ dst0,
                             const int* __restrict__ off0, int* __restrict__ cur0,
                             int* __restrict__ csr0,
                             const int* __restrict__ src1, const int* __restrict__ dst1,
                             const int* __restrict__ off1, int* __restrict__ cur1,
                             int* __restrict__ csr1) {
    int e = blockIdx.x * blockDim.x + threadIdx.x;
    const int* src = blockIdx.y ? src1 : src0;
    const int* dst = blockIdx.y ? dst1 : dst0;
    const int* off = blockIdx.y ? off1 : off0;
    int* cursor    = blockIdx.y ? cur1 : cur0;
    int* csr       = blockIdx.y ? csr1 : csr0;
    if (e < EE) {
        int d = dst[e];
        int p = atomicAdd(&cursor[d], 1);
        csr[off[d] + p] = src[e];
    }
}

// ---------------- degree sort: counting sort into perm (descending deg) ---
__global__ void hist2_kernel(const int* __restrict__ deg0, const int* __restrict__ deg1,
                             int* __restrict__ hist) {
    __shared__ int lh[64];
    if (threadIdx.x < 64) lh[threadIdx.x] = 0;
    __syncthreads();
    int n = blockIdx.x * blockDim.x + threadIdx.x;
    int g = blockIdx.y;
    const int* deg = g ? deg1 : deg0;
    if (n < NN) {
        int d = deg[n];
        int bin = 63 - ((d < 63) ? d : 63);
        atomicAdd(&lh[bin], 1);
    }
    __syncthreads();
    if (threadIdx.x < 64 && lh[threadIdx.x])
        atomicAdd(&hist[g * 64 + threadIdx.x], lh[threadIdx.x]);
}

__global__ void binoff_kernel(const int* __restrict__ hist, int* __restrict__ boff) {
    int g = threadIdx.x >> 6, lane = threadIdx.x & 63;
    int v = hist[g * 64 + lane];
    int x = v;
#pragma unroll
    for (int s = 1; s < 64; s <<= 1) {
        int t = __shfl_up(x, s, 64);
        if (lane >= s) x += t;
    }
    boff[g * 64 + lane] = x - v;
}

__global__ void permfill2_kernel(const int* __restrict__ deg0, const int* __restrict__ deg1,
                                 const int* __restrict__ boff, int* __restrict__ bcur,
                                 int* __restrict__ perm0, int* __restrict__ perm1) {
    __shared__ int lh[64], lbase[64];
    if (threadIdx.x < 64) lh[threadIdx.x] = 0;
    __syncthreads();
    int n = blockIdx.x * blockDim.x + threadIdx.x;
    int g = blockIdx.y;
    const int* deg = g ? deg1 : deg0;
    int* perm      = g ? perm1 : perm0;
    int bin = 0, myp = 0;
    if (n < NN) {
        int d = deg[n];
        bin = 63 - ((d < 63) ? d : 63);
        myp = atomicAdd(&lh[bin], 1);
    }
    __syncthreads();
    if (threadIdx.x < 64) {
        int c = lh[threadIdx.x];
        lbase[threadIdx.x] = c ? atomicAdd(&bcur[g * 64 + threadIdx.x], c) : 0;
    }
    __syncthreads();
    if (n < NN) perm[boff[g * 64 + bin] + lbase[bin] + myp] = n;
}

// ---------------- precompute vl/vr for all 8 GATs ----------------
__global__ void vpre_kernel(const float* __restrict__ fc0, const float* __restrict__ al0, const float* __restrict__ ar0,
                            const float* __restrict__ fc1, const float* __restrict__ al1, const float* __restrict__ ar1,
                            const float* __restrict__ fc2, const float* __restrict__ al2, const float* __restrict__ ar2,
                            const float* __restrict__ fc3, const float* __restrict__ al3, const float* __restrict__ ar3,
                            float* __restrict__ vbuf) {
    int j = threadIdx.x;                 // 0..319
    if (j >= 320) return;
    int g = j / 40, r = j % 40;
    int h = r / 10, t = r % 10;
    int which = g & 3, layer = g >> 2;
    const float* fc; const float* al; const float* ar;
    if (which == 0)      { fc = fc0; al = al0; ar = ar0; }
    else if (which == 1) { fc = fc1; al = al1; ar = ar1; }
    else if (which == 2) { fc = fc2; al = al2; ar = ar2; }
    else                 { fc = fc3; al = al3; ar = ar3; }
    fc += layer * (HH * DD * TT);
    al += layer * (HH * DD);
    ar += layer * (HH * DD);
    float vl = 0.f, vr = 0.f;
#pragma unroll
    for (int d = 0; d < DD; d++) {
        float w = fc[(h * DD + d) * TT + t];
        vl += al[h * DD + d] * w;
        vr += ar[h * DD + d] * w;
    }
    vbuf[g * 80 + r] = vl;
    vbuf[g * 80 + 40 + r] = vr;
}

// ---------------- pair-GAT: fp16 rows + batch-group blocking --------------
struct PairCfg {
    const __half* f;                // DUALF: 24 halves/row (A=+0,B=+12); else 16 halves shared
    const float* WA; const float* WB;
    const float* vA; const float* vB;
    const int* off; const int* csr; const int* perm;
    float* gA; float* gB;
    float* statsA; float* statsB;
};
struct PairCfg2 { PairCfg c[2]; };

__device__ __forceinline__ void eacc(const float (&fa)[TT], bool val,
                                     const float* __restrict__ v,
                                     const float (&er)[HH],
                                     float (&den)[HH], float (&acc)[HH][TT]) {
#pragma unroll
    for (int h = 0; h < HH; h++) {
        float e = 0.f;
#pragma unroll
        for (int t = 0; t < TT; t++) e += v[h * TT + t] * fa[t];
        float z = e + er[h];
        z = (z >= 0.f) ? z : NEG * z;
        float w = val ? __expf(z) : 0.f;
        den[h] += w;
#pragma unroll
        for (int t = 0; t < TT; t++) acc[h][t] += w * fa[t];
    }
}

template <bool DUALF, bool STATS>
__global__ void __launch_bounds__(256)
gatpair_kernel(PairCfg2 cfgs) {
    const PairCfg cfg = cfgs.c[blockIdx.y];
    __shared__ __align__(16) float sWA[HH * DD * 12];
    __shared__ __align__(16) float sWB[HH * DD * 12];
    for (int kk = threadIdx.x; kk < HH * DD * TT; kk += blockDim.x) {
        int r = kk / TT, t = kk - r * TT;
        sWA[r * 12 + t] = cfg.WA[kk];
        sWB[r * 12 + t] = cfg.WB[kk];
    }
    __syncthreads();

    const __half* __restrict__ f  = cfg.f;
    const int*   __restrict__ csr = cfg.csr;
    const float* __restrict__ vA  = cfg.vA;
    const float* __restrict__ vB  = cfg.vB;
    const int LDR = DUALF ? 24 : 16;   // halves per row

    int i = blockIdx.x * blockDim.x + threadIdx.x;   // over NB (bgrp-major)
    float lsA = 0.f, lqA = 0.f, lsB = 0.f, lqB = 0.f;
    if (i < NB) {
        // batch-group blocking: co-resident blocks share bgrp -> L2-resident slice
        int bgrp = i / NGRP;
        int r = i - bgrp * NGRP;
        int slot = r >> 1;               // BSUB=2
        int b = (bgrp << 1) | (r & 1);
        int n = cfg.perm[slot];          // degree-sorted: wave's 32 slots ~equal deg
        int nb = n * BB + b;
        int s0 = cfg.off[n], s1 = cfg.off[n + 1];

        // er from self features, both GATs
        float erA[HH], erB[HH];
        {
            const uint4* p = (const uint4*)(f + (size_t)nb * LDR);
            float fsA[TT], fsB[TT];
            if (DUALF) {
                uint4 u0 = p[0], u1 = p[1], u2 = p[2];
                unpA(u0, u1, fsA); unpB(u1, u2, fsB);
            } else {
                uint4 u0 = p[0], u1 = p[1];
                unpA(u0, u1, fsA);
#pragma unroll
                for (int t = 0; t < TT; t++) fsB[t] = fsA[t];
            }
#pragma unroll
            for (int h = 0; h < HH; h++) {
                float ea = 0.f, eb = 0.f;
#pragma unroll
                for (int t = 0; t < TT; t++) {
                    ea += vA[HH * TT + h * TT + t] * fsA[t];
                    eb += vB[HH * TT + h * TT + t] * fsB[t];
                }
                erA[h] = ea; erB[h] = eb;
            }
        }

        float accA[HH][TT], accB[HH][TT];
        float denA[HH], denB[HH];
#pragma unroll
        for (int h = 0; h < HH; h++) {
            denA[h] = 0.f; denB[h] = 0.f;
#pragma unroll
            for (int t = 0; t < TT; t++) { accA[h][t] = 0.f; accB[h][t] = 0.f; }
        }

        // unroll-4 edge loop; masked slots clamp to s0 (L1-hot dud row, w=0)
        for (int k = s0; k < s1; k += 4) {
            int k1 = (k + 1 < s1) ? k + 1 : s0;
            int k2 = (k + 2 < s1) ? k + 2 : s0;
            int k3 = (k + 3 < s1) ? k + 3 : s0;
            bool v1 = (k + 1 < s1), v2 = (k + 2 < s1), v3 = (k + 3 < s1);
            int e0 = csr[k], e1 = csr[k1], e2 = csr[k2], e3 = csr[k3];
            const uint4* q0 = (const uint4*)(f + (size_t)(e0 * BB + b) * LDR);
            const uint4* q1 = (const uint4*)(f + (size_t)(e1 * BB + b) * LDR);
            const uint4* q2 = (const uint4*)(f + (size_t)(e2 * BB + b) * LDR);
            const uint4* q3 = (const uint4*)(f + (size_t)(e3 * BB + b) * LDR);
            if (DUALF) {
                uint4 a0 = q0[0], a1 = q0[1], a2 = q0[2];
                uint4 b0 = q1[0], b1 = q1[1], b2 = q1[2];
                uint4 c0 = q2[0], c1 = q2[1], c2 = q2[2];
                uint4 d0 = q3[0], d1 = q3[1], d2 = q3[2];
                float fa[TT], fb[TT];
                unpA(a0, a1, fa); unpB(a1, a2, fb);
                eacc(fa, true, vA, erA, denA, accA); eacc(fb, true, vB, erB, denB, accB);
                unpA(b0, b1, fa); unpB(b1, b2, fb);
                eacc(fa, v1, vA, erA, denA, accA);   eacc(fb, v1, vB, erB, denB, accB);
                unpA(c0, c1, fa); unpB(c1, c2, fb);
                eacc(fa, v2, vA, erA, denA, accA);   eacc(fb, v2, vB, erB, denB, accB);
                unpA(d0, d1, fa); unpB(d1, d2, fb);
                eacc(fa, v3, vA, erA, denA, accA);   eacc(fb, v3, vB, erB, denB, accB);
            } else {
                uint4 a0 = q0[0], a1 = q0[1];
                uint4 b0 = q1[0], b1 = q1[1];
                uint4 c0 = q2[0], c1 = q2[1];
                uint4 d0 = q3[0], d1 = q3[1];
                float fa[TT];
                unpA(a0, a1, fa);
                eacc(fa, true, vA, erA, denA, accA); eacc(fa, true, vB, erB, denB, accB);
                unpA(b0, b1, fa);
                eacc(fa, v1, vA, erA, denA, accA);   eacc(fa, v1, vB, erB, denB, accB);
                unpA(c0, c1, fa);
                eacc(fa, v2, vA, erA, denA, accA);   eacc(fa, v2, vB, erB, denB, accB);
                unpA(d0, d1, fa);
                eacc(fa, v3, vA, erA, denA, accA);   eacc(fa, v3, vB, erB, denB, accB);
            }
        }

        bool nz = (s1 > s0);
        float* gpA = cfg.gA + (size_t)nb * DD;
        float* gpB = cfg.gB + (size_t)nb * DD;

#pragma unroll
        for (int g = 0; g < 2; g++) {
            const float (*acc)[TT] = g ? accB : accA;
            const float* den = g ? denB : denA;
            const float* sW  = g ? sWB : sWA;
            float* gp        = g ? gpB : gpA;
            float rd[HH];
#pragma unroll
            for (int h = 0; h < HH; h++) rd[h] = nz ? (1.0f / den[h]) : 0.f;
            float outv[DD];
#pragma unroll
            for (int d = 0; d < DD; d++) outv[d] = 0.f;
#pragma unroll
            for (int h = 0; h < HH; h++) {
#pragma unroll
                for (int d = 0; d < DD; d++) {
                    const float* wr = &sW[(h * DD + d) * 12];
                    float4 w0 = *(const float4*)wr;
                    float4 w1 = *(const float4*)(wr + 4);
                    float2 w2 = *(const float2*)(wr + 8);
                    float va = w0.x * acc[h][0] + w0.y * acc[h][1] + w0.z * acc[h][2] + w0.w * acc[h][3]
                             + w1.x * acc[h][4] + w1.y * acc[h][5] + w1.z * acc[h][6] + w1.w * acc[h][7]
                             + w2.x * acc[h][8] + w2.y * acc[h][9];
                    va *= rd[h];
                    va = (va >= 0.f) ? va : NEG * va;
                    outv[d] += va * 0.25f;
                }
            }
#pragma unroll
            for (int d = 0; d < DD; d += 2)
                *(float2*)(gp + d) = make_float2(outv[d], outv[d + 1]);
            if (STATS) {
                float s = 0.f, q = 0.f;
#pragma unroll
                for (int d = 0; d < DD; d++) { s += outv[d]; q += outv[d] * outv[d]; }
                if (g) { lsB = s; lqB = q; } else { lsA = s; lqA = q; }
            }
        }
    }
    if (STATS) {
#pragma unroll
        for (int o = 32; o > 0; o >>= 1) {
            lsA += __shfl_down(lsA, o, 64);
            lqA += __shfl_down(lqA, o, 64);
            lsB += __shfl_down(lsB, o, 64);
            lqB += __shfl_down(lqB, o, 64);
        }
        __shared__ float ss[4][4];
        int wid = threadIdx.x >> 6, lid = threadIdx.x & 63;
        if (lid == 0) { ss[wid][0] = lsA; ss[wid][1] = lqA; ss[wid][2] = lsB; ss[wid][3] = lqB; }
        __syncthreads();
        if (threadIdx.x == 0) {
            float a0 = 0.f, a1 = 0.f, a2 = 0.f, a3 = 0.f;
#pragma unroll
            for (int w = 0; w < 4; w++) { a0 += ss[w][0]; a1 += ss[w][1]; a2 += ss[w][2]; a3 += ss[w][3]; }
            atomicAdd(&cfg.statsA[0], a0);
            atomicAdd(&cfg.statsA[1], a1);
            atomicAdd(&cfg.statsB[0], a2);
            atomicAdd(&cfg.statsB[1], a3);
        }
    }
}

// ---------------- LN(A), LN(B), average; writes fp16 rows (16 halves) -----
__global__ void lncomb2_kernel(const float* __restrict__ gA, const float* __restrict__ gB,
                               const float* __restrict__ gA2, const float* __restrict__ gB2,
                               const float* __restrict__ stats,
                               __half* __restrict__ hp, __half* __restrict__ hrl) {
    int i = blockIdx.x * blockDim.x + threadIdx.x;   // over NB*8 half2-pairs
    if (i >= NB * 8) return;
    const float* ga = blockIdx.y ? gA2 : gA;
    const float* gb = blockIdx.y ? gB2 : gB;
    const float* st = stats + (blockIdx.y ? 4 : 0);
    __half2* h      = (__half2*)(blockIdx.y ? hrl : hp);
    int nb = i >> 3, t2 = i & 7;
    float v0 = 0.f, v1 = 0.f;
    if (t2 < 5) {
        const float M = (float)NBT;
        float ma = st[0] / M; float va = st[1] / M - ma * ma;
        float mb = st[2] / M; float vb = st[3] / M - mb * mb;
        float ra = rsqrtf(va + 1e-5f), rb = rsqrtf(vb + 1e-5f);
        size_t base = (size_t)nb * DD + t2 * 2;
        v0 = 0.5f * ((ga[base] - ma) * ra + (gb[base] - mb) * rb);
        v1 = 0.5f * ((ga[base + 1] - ma) * ra + (gb[base + 1] - mb) * rb);
    }
    h[(size_t)nb * 8 + t2] = __floats2half2_rn(v0, v1);
}

// ---------------- final combine, both outputs in one dispatch -------------
__global__ void outcomb2_kernel(const float* __restrict__ regmu, const float* __restrict__ regsg,
                                const float* __restrict__ gA, const float* __restrict__ gA2,
                                const float* __restrict__ gB, const float* __restrict__ gB2,
                                float* __restrict__ out) {
    int i = blockIdx.x * blockDim.x + threadIdx.x;
    if (i >= NBT) return;
    int nb = i / DD;
    if (blockIdx.y == 0) out[i]       = (regmu[nb] + gA[i] + gA2[i]) * (1.0f / 3.0f);
    else                 out[NBT + i] = (regsg[nb] + gB[i] + gB2[i]) * (1.0f / 3.0f);
}

extern "C" void kernel_launch(void* const* d_in, const int* in_sizes, int n_in,
                              void* d_out, int out_size, void* d_ws, size_t ws_size,
                              hipStream_t stream) {
    const float* x      = (const float*)d_in[0];
    const int* ps_src   = (const int*)d_in[1];
    const int* ps_dst   = (const int*)d_in[2];
    const int* rl_src   = (const int*)d_in[3];
    const int* rl_dst   = (const int*)d_in[4];
    const float* mu_p_fc = (const float*)d_in[5];
    const float* mu_p_al = (const float*)d_in[6];
    const float* mu_p_ar = (const float*)d_in[7];
    const float* sg_p_fc = (const float*)d_in[8];
    const float* sg_p_al = (const float*)d_in[9];
    const float* sg_p_ar = (const float*)d_in[10];
    const float* mu_r_fc = (const float*)d_in[11];
    const float* mu_r_al = (const float*)d_in[12];
    const float* mu_r_ar = (const float*)d_in[13];
    const float* sg_r_fc = (const float*)d_in[14];
    const float* sg_r_al = (const float*)d_in[15];
    const float* sg_r_ar = (const float*)d_in[16];
    const float* reg_mu_w = (const float*)d_in[17];
    const float* reg_mu_b = (const float*)d_in[18];
    const float* reg_sg_w = (const float*)d_in[19];
    const float* reg_sg_b = (const float*)d_in[20];

    float* out = (float*)d_out;

    // ---- workspace carve (counts in floats) ----
    float* fw = (float*)d_ws;
    __half* msH  = (__half*)fw;     fw += NB * 12;   // 24 halves/row
    __half* hpH  = (__half*)fw;     fw += NB * 8;    // 16 halves/row
    __half* hrlH = (__half*)fw;     fw += NB * 8;
    float* gA    = fw;              fw += NBT;       // fp32 GAT outputs, stride 10
    float* gB    = fw;              fw += NBT;
    float* gA2   = fw;              fw += NBT;
    float* gB2   = fw;              fw += NBT;
    float* regmu = fw;              fw += NB;
    float* regsg = fw;              fw += NB;
    float* vbuf  = fw;              fw += 8 * 80;
    int* iw = (int*)fw;
    int* ps_off = iw;               iw += NN + 1;
    int* rl_off = iw;               iw += NN + 1;
    int* ps_csr = iw;               iw += EE;
    int* rl_csr = iw;               iw += EE;
    int* perm_ps = iw;              iw += NN;
    int* perm_rl = iw;              iw += NN;
    int* boff   = iw;               iw += 128;
    // zero region starts here:
    int* deg_ps = iw;               iw += NN;
    int* cur_ps = iw;               iw += NN;
    int* deg_rl = iw;               iw += NN;
    int* cur_rl = iw;               iw += NN;
    int* hist   = iw;               iw += 128;
    int* bcur   = iw;               iw += 128;
    float* stats = (float*)iw;      // 8 floats
    size_t zero_bytes = (size_t)(4 * NN + 256) * sizeof(int) + 8 * sizeof(float);
    hipMemsetAsync(deg_ps, 0, zero_bytes, stream);

    const int TPB = 256;
    const int GRID_NB  = (NB + TPB - 1) / TPB;          // 1250
    const int GRID_NBT = (NBT + TPB - 1) / TPB;
    const int GRID_LN  = (NB * 8 + TPB - 1) / TPB;      // 10000
    const int GRID_E   = (EE + TPB - 1) / TPB;
    const int GRID_N   = (NN + TPB - 1) / TPB;          // 40

    extract_kernel<<<GRID_NB, TPB, 0, stream>>>(x, reg_mu_w, reg_mu_b, reg_sg_w, reg_sg_b,
                                                msH, regmu, regsg);

    // CSR + degree-sort for both graphs
    {
        dim3 g(GRID_E, 2, 1);
        dim3 gn(GRID_N, 2, 1);
        deg2_kernel<<<g, TPB, 0, stream>>>(ps_dst, deg_ps, rl_dst, deg_rl);
        scan2_kernel<<<2, 1024, 0, stream>>>(deg_ps, ps_off, deg_rl, rl_off);
        fill2_kernel<<<g, TPB, 0, stream>>>(ps_src, ps_dst, ps_off, cur_ps, ps_csr,
                                            rl_src, rl_dst, rl_off, cur_rl, rl_csr);
        hist2_kernel<<<gn, TPB, 0, stream>>>(deg_ps, deg_rl, hist);
        binoff_kernel<<<1, 128, 0, stream>>>(hist, boff);
        permfill2_kernel<<<gn, TPB, 0, stream>>>(deg_ps, deg_rl, boff, bcur, perm_ps, perm_rl);
    }

    vpre_kernel<<<1, 320, 0, stream>>>(mu_p_fc, mu_p_al, mu_p_ar,
                                       sg_p_fc, sg_p_al, sg_p_ar,
                                       mu_r_fc, mu_r_al, mu_r_ar,
                                       sg_r_fc, sg_r_al, sg_r_ar, vbuf);

    // ---- layer 0: 2 pairs on interleaved fp16 ms ----
    {
        PairCfg2 c;
        c.c[0] = { msH, mu_p_fc, sg_p_fc, vbuf + 0 * 80, vbuf + 1 * 80,
                   ps_off, ps_csr, perm_ps, gA,  gB,  stats + 0, stats + 2 };
        c.c[1] = { msH, mu_r_fc, sg_r_fc, vbuf + 2 * 80, vbuf + 3 * 80,
                   rl_off, rl_csr, perm_rl, gA2, gB2, stats + 4, stats + 6 };
        dim3 grid(GRID_NB, 2, 1);
        gatpair_kernel<true, true><<<grid, TPB, 0, stream>>>(c);
    }
    {
        dim3 g(GRID_LN, 2, 1);
        lncomb2_kernel<<<g, TPB, 0, stream>>>(gA, gB, gA2, gB2, stats, hpH, hrlH);
    }

    // ---- final layers: 2 pairs, shared fp16 row per pair ----
    {
        PairCfg2 c;
        c.c[0] = { hpH,  mu_p_fc + 400, sg_p_fc + 400, vbuf + 4 * 80, vbuf + 5 * 80,
                   ps_off, ps_csr, perm_ps, gA,  gB,  nullptr, nullptr };
        c.c[1] = { hrlH, mu_r_fc + 400, sg_r_fc + 400, vbuf + 6 * 80, vbuf + 7 * 80,
                   rl_off, rl_csr, perm_rl, gA2, gB2, nullptr, nullptr };
        dim3 grid(GRID_NB, 2, 1);
        gatpair_kernel<false, false><<<grid, TPB, 0, stream>>>(c);
    }

    {
        dim3 g(GRID_NBT, 2, 1);
        outcomb2_kernel<<<g, TPB, 0, stream>>>(regmu, regsg, gA, gA2, gB, gB2, out);
    }
}